// Round 6
// baseline (1584.127 us; speedup 1.0000x reference)
//
#include <hip/hip_runtime.h>

// SparseFinerAttention on MI355X — round 6 (DPP reduces + 8-row blocks for 2 blocks/CU)
// B=2 N=4096 C=768 H=12 D=64 SCALE=1/8 K_keep=409

typedef unsigned short u16;
typedef unsigned int   u32;
typedef float    f32x4 __attribute__((ext_vector_type(4)));
typedef _Float16 f16x8 __attribute__((ext_vector_type(8)));
typedef u16      u16x8 __attribute__((ext_vector_type(8)));
typedef u16      u16x4 __attribute__((ext_vector_type(4)));
typedef u32      u32x4 __attribute__((ext_vector_type(4)));

#define NHEADS 12
#define SEQ    4096
#define DIMC   768
#define HDIM   64
#define KKEEP  409
#define QROWS  8            // q rows per block (8 waves, 2 blocks/CU)

__device__ __forceinline__ f32x4 mfma16(f16x8 a, f16x8 b, f32x4 c) {
  return __builtin_amdgcn_mfma_f32_16x16x32_f16(a, b, c, 0, 0, 0);
}
__device__ __forceinline__ u16 f2h_bits(float f) {
  return __builtin_bit_cast(u16, (_Float16)f);
}

// GPUOpen canonical wave64 DPP reduce: row_shr 1/2/4/8 + row_bcast 15/31, total in lane 63.
__device__ __forceinline__ u32 wred_add_u32(u32 x) {
  x += (u32)__builtin_amdgcn_update_dpp(0, (int)x, 0x111, 0xF, 0xF, true); // row_shr:1
  x += (u32)__builtin_amdgcn_update_dpp(0, (int)x, 0x112, 0xF, 0xF, true); // row_shr:2
  x += (u32)__builtin_amdgcn_update_dpp(0, (int)x, 0x114, 0xF, 0xF, true); // row_shr:4
  x += (u32)__builtin_amdgcn_update_dpp(0, (int)x, 0x118, 0xF, 0xF, true); // row_shr:8
  x += (u32)__builtin_amdgcn_update_dpp(0, (int)x, 0x142, 0xF, 0xF, true); // row_bcast:15
  x += (u32)__builtin_amdgcn_update_dpp(0, (int)x, 0x143, 0xF, 0xF, true); // row_bcast:31
  return (u32)__builtin_amdgcn_readlane((int)x, 63);
}
__device__ __forceinline__ float wred_add_f32(float x) {
#define _DPPF(ctrl) x += __builtin_bit_cast(float, __builtin_amdgcn_update_dpp( \
      0, __builtin_bit_cast(int, x), ctrl, 0xF, 0xF, true));
  _DPPF(0x111) _DPPF(0x112) _DPPF(0x114) _DPPF(0x118) _DPPF(0x142) _DPPF(0x143)
#undef _DPPF
  return __builtin_bit_cast(float, __builtin_amdgcn_readlane(__builtin_bit_cast(int, x), 63));
}

// ---------------- cast fp32 -> fp16 (vectorized) ----------------
__global__ __launch_bounds__(256) void cast_f32_to_f16(const float* __restrict__ in,
                                                       u16* __restrict__ out, int n4) {
  int i = blockIdx.x * 256 + threadIdx.x;
  if (i >= n4) return;
  float4 v = ((const float4*)in)[i];
  u16x4 o;
  o[0] = f2h_bits(v.x); o[1] = f2h_bits(v.y); o[2] = f2h_bits(v.z); o[3] = f2h_bits(v.w);
  ((u16x4*)out)[i] = o;
}

// ---------------- NT GEMM: C[M][768] = A[M][768] @ B[768][768]^T ----------------
template<int MODE>
__global__ __launch_bounds__(256) void gemm_nt(const u16* __restrict__ A, const u16* __restrict__ B,
                                               float scale, const float* __restrict__ bias,
                                               void* __restrict__ dstv) {
  __shared__ __align__(16) u16 As[128 * 64];
  __shared__ __align__(16) u16 Bs[128 * 64];
  const int tid  = threadIdx.x;
  const int lane = tid & 63, wave = tid >> 6;
  const int l15 = lane & 15, l4 = lane >> 4;
  const int row0 = blockIdx.x * 128, col0 = blockIdx.y * 128;
  const int wr = (wave >> 1) * 64, wc = (wave & 1) * 64;
  f32x4 acc[4][4];
#pragma unroll
  for (int i = 0; i < 4; i++)
#pragma unroll
    for (int j = 0; j < 4; j++) acc[i][j] = f32x4{0.f, 0.f, 0.f, 0.f};

  for (int k0 = 0; k0 < DIMC; k0 += 64) {
#pragma unroll
    for (int i = 0; i < 4; i++) {
      int id = tid + i * 256;
      int r = id >> 3, c = id & 7;
      f16x8 va = *(const f16x8*)(A + (size_t)(row0 + r) * DIMC + k0 + c * 8);
      f16x8 vb = *(const f16x8*)(B + (size_t)(col0 + r) * DIMC + k0 + c * 8);
      *(f16x8*)(As + r * 64 + ((c ^ (r & 7)) << 3)) = va;
      *(f16x8*)(Bs + r * 64 + ((c ^ (r & 7)) << 3)) = vb;
    }
    __syncthreads();
#pragma unroll
    for (int ks = 0; ks < 2; ++ks) {
      f16x8 af[4], bfr[4];
#pragma unroll
      for (int i = 0; i < 4; i++) {
        int r = wr + i * 16 + l15;
        int c = ks * 4 + l4;
        af[i] = *(const f16x8*)(As + r * 64 + ((c ^ (r & 7)) << 3));
        int r2 = wc + i * 16 + l15;
        bfr[i] = *(const f16x8*)(Bs + r2 * 64 + ((c ^ (r2 & 7)) << 3));
      }
#pragma unroll
      for (int i = 0; i < 4; i++)
#pragma unroll
        for (int j = 0; j < 4; j++) acc[i][j] = mfma16(af[i], bfr[j], acc[i][j]);
    }
    __syncthreads();
  }

#pragma unroll
  for (int i = 0; i < 4; i++) {
#pragma unroll
    for (int j = 0; j < 4; j++) {
      int rowb = row0 + wr + i * 16 + (l4 << 2);
      int col  = col0 + wc + j * 16 + l15;
      if (MODE == 2) {
        float* dst = (float*)dstv;
        float bv = bias[col];
#pragma unroll
        for (int jj = 0; jj < 4; jj++)
          dst[(size_t)(rowb + jj) * DIMC + col] = acc[i][j][jj] + bv;
      } else if (MODE == 0) {
        u16* dst = (u16*)dstv;
        int hh = col >> 6, d = col & 63;
#pragma unroll
        for (int jj = 0; jj < 4; jj++) {
          int row = rowb + jj;
          int bb = row >> 12, n = row & 4095;
          dst[(((size_t)bb * NHEADS + hh) * SEQ + n) * HDIM + d] = f2h_bits(acc[i][j][jj] * scale);
        }
      } else { // MODE 1: V transposed [b][h][d][n]
        u16* dst = (u16*)dstv;
        int hh = col >> 6, d = col & 63;
        int bb = rowb >> 12, nb = rowb & 4095;
        u16x4 pack;
#pragma unroll
        for (int jj = 0; jj < 4; jj++) pack[jj] = f2h_bits(acc[i][j][jj] * scale);
        *(u16x4*)(dst + (((size_t)bb * NHEADS + hh) * HDIM + d) * SEQ + nb) = pack;
      }
    }
  }
}

// ---------------- fused attention ----------------
// 1 workgroup (512 thr, 8 waves) per (b, h, 8-row q block); 2 blocks/CU.
// QK^T:  wave w keys [w*512,(w+1)*512) via swapped mfma(K,Q) (q rows duplicated into
//        cols 8-15, stores gated to l15<8); stores fp16(exp(logit)); f32 Z partials.
// top-k: wave w owns row w; SWAR binary search, DPP wave reduce (scalar loop state).
// PV:    wave w covers its 512 keys on unnormalized P̃; invZ applied in epilogue.
// S: [8][4096] fp16, XOR-swizzled: sidx(q,m) = q*4096 + (((m>>3) ^ (q&7))<<3 | (m&7))
__global__ __launch_bounds__(512, 4) void attn_kernel(const u16* __restrict__ Q, const u16* __restrict__ Kb,
                                                      const u16* __restrict__ Vt, u16* __restrict__ Ob) {
  __shared__ __align__(16) u16 S[QROWS * 4096];   // 64 KB (re-used for fp32 O-partials)
  __shared__ float zbuf[QROWS][32];               // per-row Z partials [row][wave*4+l4]
  __shared__ float invZs[QROWS];
  const int tid  = threadIdx.x;
  const int lane = tid & 63, wave = tid >> 6;     // 8 waves
  const int l15 = lane & 15, l4 = lane >> 4;
  const int r7  = l15 & 7;
  const int h = blockIdx.y, b = blockIdx.z;
  const int bh = b * NHEADS + h;
  const int q0 = blockIdx.x * QROWS;
  const u16* Qh = Q  + ((size_t)bh * SEQ + q0) * HDIM;
  const u16* Kh = Kb + (size_t)bh * SEQ * HDIM;
  const u16* Vh = Vt + (size_t)bh * HDIM * SEQ;

  // Q fragments: 8 real rows duplicated into cols 8-15 (B-operand col = l15)
  f16x8 qa0 = *(const f16x8*)(Qh + r7 * HDIM + l4 * 8);
  f16x8 qa1 = *(const f16x8*)(Qh + r7 * HDIM + 32 + l4 * 8);

  // ---- QK^T (swapped) + exp + Z partial: wave w covers keys [w*512, (w+1)*512) ----
  const int m0base = wave * 512;
  float zp = 0.f;
  {
    const u16* kptr = Kh + (size_t)(m0base + l15) * HDIM + l4 * 8;
    f16x8 kb0 = *(const f16x8*)kptr;
    f16x8 kb1 = *(const f16x8*)(kptr + 32);
#pragma unroll 1
    for (int t = 0; t < 32; ++t) {
      f16x8 cur0 = kb0, cur1 = kb1;
      if (t < 31) {
        const u16* kpn = Kh + (size_t)(m0base + (t + 1) * 16 + l15) * HDIM + l4 * 8;
        kb0 = *(const f16x8*)kpn;
        kb1 = *(const f16x8*)(kpn + 32);
      }
      f32x4 acc = f32x4{0.f, 0.f, 0.f, 0.f};
      acc = mfma16(cur0, qa0, acc);
      acc = mfma16(cur1, qa1, acc);
      int m0 = m0base + t * 16;
      int g = (m0 >> 3) + (l4 >> 1);
      u16x4 pack;
#pragma unroll
      for (int j = 0; j < 4; j++) {
        float e = __expf(fminf(acc[j], 11.0f));
        zp += e;
        pack[j] = f2h_bits(e);
      }
      if (l15 < 8)   // cols 8-15 are duplicate q rows
        *(u16x4*)(S + (l15 << 12) + ((g ^ r7) << 3) + ((l4 & 1) << 2)) = pack;
    }
  }
  if (l15 < 8) zbuf[l15][(wave << 2) + l4] = zp;
  __syncthreads();

  // ---- exact top-k(409) per row; wave w owns row w ----
  {
    const u32 rbase = (u32)wave << 12;
    const u32 rx = (u32)(wave & 7) << 3;
    const u32 H = 0x80008000u;
    u32 X[8][4];
#pragma unroll
    for (int cc = 0; cc < 8; ++cc) {
      u32 c = (u32)cc * 64 + lane;
      u32x4 v = *(const u32x4*)(S + rbase + ((c << 3) ^ rx));
#pragma unroll
      for (int p = 0; p < 4; p++) X[cc][p] = v[p] | H;
    }
    // binary search on [0,0x7FFF]: t = smallest v with count(key > v) < KKEEP
    u32 lo = 0, hi = 0x7FFFu, c1 = 0;
    while (lo < hi) {
      u32 mid = (lo + hi) >> 1;
      u32 M1 = (mid + 1) * 0x10001u;
      u32 pc = 0;
#pragma unroll
      for (int cc = 0; cc < 8; ++cc)
#pragma unroll
        for (int p = 0; p < 4; p++) {
          u32 d = X[cc][p] - M1;
          pc += (d & H) >> 15;
        }
      u32 s = wred_add_u32(pc);                    // DPP reduce, scalar result
      u32 cnt = (s & 0xFFFFu) + (s >> 16);
      if (cnt < KKEEP) { hi = mid; c1 = cnt; } else lo = mid + 1;
    }
    const u32 t = lo;
    // Z reduce (partials from QK^T phase)
    float z = (lane < 32) ? zbuf[wave][lane] : 0.f;
    z = wred_add_f32(z);
    if (lane == 0) invZs[wave] = 1.f / z;
    const int r = KKEEP - (int)c1;

    // write-back masked (unnormalized) weights
    const u32 M1t = (t + 1) * 0x10001u;
    const u32 M0t = t * 0x10001u;
    int run = 0;
#pragma unroll 1
    for (int cc = 0; cc < 8; ++cc) {
      u32 g1[4], eqm[4], eqany = 0;
#pragma unroll
      for (int p = 0; p < 4; p++) {
        u32 x = X[cc][p];
        g1[p] = (x - M1t) & H;
        u32 g0 = (x - M0t) & H;
        eqm[p] = g0 ^ g1[p];
        eqany |= eqm[p];
      }
      u32 c = (u32)cc * 64 + lane;
      u32* dst = (u32*)(S + rbase + ((c << 3) ^ rx));
      if (!__any(eqany != 0)) {                    // tie-free chunk: branchless masks
        u32x4 o;
#pragma unroll
        for (int p = 0; p < 4; p++) {
          u32 m = g1[p] | (g1[p] - (g1[p] >> 15));
          o[p] = X[cc][p] & m & 0x7FFF7FFFu;
        }
        *(u32x4*)dst = o;
      } else {                                     // rare: exact tie ranking
        u32 s = 0;
#pragma unroll
        for (int p = 0; p < 4; p++) s += eqm[p] >> 15;
        int ec = (int)((s & 0xFFFFu) + (s >> 16));
        int inc = ec;
#pragma unroll
        for (int o = 1; o < 64; o <<= 1) { int pfx = __shfl_up(inc, o); if (lane >= o) inc += pfx; }
        int rk = run + inc - ec;
        run += __shfl(inc, 63);
        u32x4 o;
#pragma unroll
        for (int p = 0; p < 4; p++) {
          u32 x = X[cc][p];
          u32 glo = (g1[p] >> 15) & 1u, ghi = g1[p] >> 31;
          u32 elo = (eqm[p] >> 15) & 1u, ehi = eqm[p] >> 31;
          u32 klo = glo | (elo & (rk < r ? 1u : 0u)); rk += (int)elo;
          u32 khi = ghi | (ehi & (rk < r ? 1u : 0u)); rk += (int)ehi;
          o[p] = x & ((klo ? 0xFFFFu : 0u) | (khi ? 0xFFFF0000u : 0u)) & 0x7FFF7FFFu;
        }
        *(u32x4*)dst = o;
      }
    }
  }
  __syncthreads();

  // ---- masked dense PV on unnormalized P̃; wave w covers its 512 keys ----
  f32x4 oacc[4];
#pragma unroll
  for (int dt = 0; dt < 4; dt++) oacc[dt] = f32x4{0.f, 0.f, 0.f, 0.f};
#pragma unroll 1
  for (int ks = 0; ks < 16; ++ks) {
    int mb = wave * 512 + ks * 32;
    u32 c = (u32)(mb >> 3) + l4;
    f16x8 pa = *(const f16x8*)(S + (r7 << 12) + ((c ^ r7) << 3));
#pragma unroll
    for (int dt = 0; dt < 4; ++dt) {
      const u16* vp = Vh + (size_t)(dt * 16 + l15) * SEQ + mb + l4 * 8;
      f16x8 vb = *(const f16x8*)vp;
      oacc[dt] = mfma16(pa, vb, oacc[dt]);
    }
  }
  __syncthreads();                 // P fully consumed -> S reusable for fp32 partials
  float* Op = (float*)S;           // [8 waves][8 rows][stride 65] fp32 = 16.6 KB
  if (l4 < 2) {                    // output rows 0..7 only (8..15 are duplicates)
#pragma unroll
    for (int dt = 0; dt < 4; dt++)
#pragma unroll
      for (int j = 0; j < 4; j++)
        Op[(wave * 8 + l4 * 4 + j) * 65 + dt * 16 + l15] = oacc[dt][j];
  }
  __syncthreads();
  {
    int row = tid >> 6, d = tid & 63;   // exactly 512 outputs
    float v = 0.f;
#pragma unroll
    for (int w = 0; w < 8; ++w) v += Op[(w * 8 + row) * 65 + d];
    v *= invZs[row];                    // deferred softmax normalization
    Ob[((size_t)b * SEQ + q0 + row) * DIMC + h * HDIM + d] = f2h_bits(v);
  }
}

// ---------------- launch ----------------
extern "C" void kernel_launch(void* const* d_in, const int* in_sizes, int n_in,
                              void* d_out, int out_size, void* d_ws, size_t ws_size,
                              hipStream_t stream) {
  const float* x  = (const float*)d_in[0];
  const float* Wq = (const float*)d_in[1];
  const float* Wk = (const float*)d_in[2];
  const float* Wv = (const float*)d_in[3];
  const float* Wp = (const float*)d_in[4];
  const float* bp = (const float*)d_in[5];
  float* out = (float*)d_out;

  const size_t M = 2 * (size_t)SEQ;            // 8192
  const size_t XB = M * DIMC * 2;
  const size_t WB = (size_t)DIMC * DIMC * 2;

  char* w = (char*)d_ws;
  u16* xb   = (u16*)w; w += XB;
  u16* Wqb  = (u16*)w; w += WB;
  u16* Wkb  = (u16*)w; w += WB;
  u16* Wvb  = (u16*)w; w += WB;
  u16* Wpb  = (u16*)w; w += WB;
  u16* Qb   = (u16*)w; w += XB;
  u16* Kbuf = (u16*)w; w += XB;
  u16* Vtb  = (u16*)w; w += XB;
  u16* Obuf = (u16*)w; w += XB;

  cast_f32_to_f16<<<6144, 256, 0, stream>>>(x,  xb,  (int)(M * DIMC / 4));
  cast_f32_to_f16<<<576,  256, 0, stream>>>(Wq, Wqb, (int)(WB / 8));
  cast_f32_to_f16<<<576,  256, 0, stream>>>(Wk, Wkb, (int)(WB / 8));
  cast_f32_to_f16<<<576,  256, 0, stream>>>(Wv, Wvb, (int)(WB / 8));
  cast_f32_to_f16<<<576,  256, 0, stream>>>(Wp, Wpb, (int)(WB / 8));

  dim3 gg(64, 6);
  gemm_nt<0><<<gg, 256, 0, stream>>>(xb, Wqb, 0.125f, nullptr, Qb);    // Q pre-scaled
  gemm_nt<0><<<gg, 256, 0, stream>>>(xb, Wkb, 1.0f,   nullptr, Kbuf);
  gemm_nt<1><<<gg, 256, 0, stream>>>(xb, Wvb, 1.0f,   nullptr, Vtb);   // V transposed

  attn_kernel<<<dim3(SEQ / QROWS, NHEADS, 2), 512, 0, stream>>>(Qb, Kbuf, Vtb, Obuf);

  gemm_nt<2><<<gg, 256, 0, stream>>>(Obuf, Wpb, 1.0f, bp, out);
}

// Round 7
// 1222.079 us; speedup vs baseline: 1.2963x; 1.2963x over previous
//
#include <hip/hip_runtime.h>

// SparseFinerAttention on MI355X — round 7 (r5 structure + DPP reduces + 2-deep K prefetch)
// B=2 N=4096 C=768 H=12 D=64 SCALE=1/8 K_keep=409

typedef unsigned short u16;
typedef unsigned int   u32;
typedef float    f32x4 __attribute__((ext_vector_type(4)));
typedef _Float16 f16x8 __attribute__((ext_vector_type(8)));
typedef u16      u16x8 __attribute__((ext_vector_type(8)));
typedef u16      u16x4 __attribute__((ext_vector_type(4)));
typedef u32      u32x4 __attribute__((ext_vector_type(4)));

#define NHEADS 12
#define SEQ    4096
#define DIMC   768
#define HDIM   64
#define KKEEP  409

__device__ __forceinline__ f32x4 mfma16(f16x8 a, f16x8 b, f32x4 c) {
  return __builtin_amdgcn_mfma_f32_16x16x32_f16(a, b, c, 0, 0, 0);
}
__device__ __forceinline__ u16 f2h_bits(float f) {
  return __builtin_bit_cast(u16, (_Float16)f);
}

// GPUOpen canonical wave64 DPP reduce (verified bit-correct in round 6):
// row_shr 1/2/4/8 + row_bcast 15/31, total lands in lane 63.
__device__ __forceinline__ u32 wred_add_u32(u32 x) {
  x += (u32)__builtin_amdgcn_update_dpp(0, (int)x, 0x111, 0xF, 0xF, true); // row_shr:1
  x += (u32)__builtin_amdgcn_update_dpp(0, (int)x, 0x112, 0xF, 0xF, true); // row_shr:2
  x += (u32)__builtin_amdgcn_update_dpp(0, (int)x, 0x114, 0xF, 0xF, true); // row_shr:4
  x += (u32)__builtin_amdgcn_update_dpp(0, (int)x, 0x118, 0xF, 0xF, true); // row_shr:8
  x += (u32)__builtin_amdgcn_update_dpp(0, (int)x, 0x142, 0xF, 0xF, true); // row_bcast:15
  x += (u32)__builtin_amdgcn_update_dpp(0, (int)x, 0x143, 0xF, 0xF, true); // row_bcast:31
  return (u32)__builtin_amdgcn_readlane((int)x, 63);
}
__device__ __forceinline__ float wred_add_f32(float x) {
#define _DPPF(ctrl) x += __builtin_bit_cast(float, __builtin_amdgcn_update_dpp( \
      0, __builtin_bit_cast(int, x), ctrl, 0xF, 0xF, true));
  _DPPF(0x111) _DPPF(0x112) _DPPF(0x114) _DPPF(0x118) _DPPF(0x142) _DPPF(0x143)
#undef _DPPF
  return __builtin_bit_cast(float, __builtin_amdgcn_readlane(__builtin_bit_cast(int, x), 63));
}

// ---------------- cast fp32 -> fp16 (vectorized) ----------------
__global__ __launch_bounds__(256) void cast_f32_to_f16(const float* __restrict__ in,
                                                       u16* __restrict__ out, int n4) {
  int i = blockIdx.x * 256 + threadIdx.x;
  if (i >= n4) return;
  float4 v = ((const float4*)in)[i];
  u16x4 o;
  o[0] = f2h_bits(v.x); o[1] = f2h_bits(v.y); o[2] = f2h_bits(v.z); o[3] = f2h_bits(v.w);
  ((u16x4*)out)[i] = o;
}

// ---------------- NT GEMM: C[M][768] = A[M][768] @ B[768][768]^T ----------------
template<int MODE>
__global__ __launch_bounds__(256) void gemm_nt(const u16* __restrict__ A, const u16* __restrict__ B,
                                               float scale, const float* __restrict__ bias,
                                               void* __restrict__ dstv) {
  __shared__ __align__(16) u16 As[128 * 64];
  __shared__ __align__(16) u16 Bs[128 * 64];
  const int tid  = threadIdx.x;
  const int lane = tid & 63, wave = tid >> 6;
  const int l15 = lane & 15, l4 = lane >> 4;
  const int row0 = blockIdx.x * 128, col0 = blockIdx.y * 128;
  const int wr = (wave >> 1) * 64, wc = (wave & 1) * 64;
  f32x4 acc[4][4];
#pragma unroll
  for (int i = 0; i < 4; i++)
#pragma unroll
    for (int j = 0; j < 4; j++) acc[i][j] = f32x4{0.f, 0.f, 0.f, 0.f};

  for (int k0 = 0; k0 < DIMC; k0 += 64) {
#pragma unroll
    for (int i = 0; i < 4; i++) {
      int id = tid + i * 256;
      int r = id >> 3, c = id & 7;
      f16x8 va = *(const f16x8*)(A + (size_t)(row0 + r) * DIMC + k0 + c * 8);
      f16x8 vb = *(const f16x8*)(B + (size_t)(col0 + r) * DIMC + k0 + c * 8);
      *(f16x8*)(As + r * 64 + ((c ^ (r & 7)) << 3)) = va;
      *(f16x8*)(Bs + r * 64 + ((c ^ (r & 7)) << 3)) = vb;
    }
    __syncthreads();
#pragma unroll
    for (int ks = 0; ks < 2; ++ks) {
      f16x8 af[4], bfr[4];
#pragma unroll
      for (int i = 0; i < 4; i++) {
        int r = wr + i * 16 + l15;
        int c = ks * 4 + l4;
        af[i] = *(const f16x8*)(As + r * 64 + ((c ^ (r & 7)) << 3));
        int r2 = wc + i * 16 + l15;
        bfr[i] = *(const f16x8*)(Bs + r2 * 64 + ((c ^ (r2 & 7)) << 3));
      }
#pragma unroll
      for (int i = 0; i < 4; i++)
#pragma unroll
        for (int j = 0; j < 4; j++) acc[i][j] = mfma16(af[i], bfr[j], acc[i][j]);
    }
    __syncthreads();
  }

#pragma unroll
  for (int i = 0; i < 4; i++) {
#pragma unroll
    for (int j = 0; j < 4; j++) {
      int rowb = row0 + wr + i * 16 + (l4 << 2);
      int col  = col0 + wc + j * 16 + l15;
      if (MODE == 2) {
        float* dst = (float*)dstv;
        float bv = bias[col];
#pragma unroll
        for (int jj = 0; jj < 4; jj++)
          dst[(size_t)(rowb + jj) * DIMC + col] = acc[i][j][jj] + bv;
      } else if (MODE == 0) {
        u16* dst = (u16*)dstv;
        int hh = col >> 6, d = col & 63;
#pragma unroll
        for (int jj = 0; jj < 4; jj++) {
          int row = rowb + jj;
          int bb = row >> 12, n = row & 4095;
          dst[(((size_t)bb * NHEADS + hh) * SEQ + n) * HDIM + d] = f2h_bits(acc[i][j][jj] * scale);
        }
      } else { // MODE 1: V transposed [b][h][d][n]
        u16* dst = (u16*)dstv;
        int hh = col >> 6, d = col & 63;
        int bb = rowb >> 12, nb = rowb & 4095;
        u16x4 pack;
#pragma unroll
        for (int jj = 0; jj < 4; jj++) pack[jj] = f2h_bits(acc[i][j][jj] * scale);
        *(u16x4*)(dst + (((size_t)bb * NHEADS + hh) * HDIM + d) * SEQ + nb) = pack;
      }
    }
  }
}

// ---------------- fused attention ----------------
// 1 workgroup (1024 thr, 16 waves) per (b, h, 16-row q block).  [round-5 structure]
// QK^T:  wave w keys [w*256,(w+1)*256) via swapped mfma(K,Q); 2-deep K prefetch;
//        stores fp16(exp(logit)) (monotone -> same top-k); f32 Z partials.
// top-k: wave w owns row w; SWAR packed binary search, DPP wave reduces (no bpermute).
// PV:    wave w covers its 256 keys on unnormalized P̃; invZ applied in epilogue.
// S: [16][4096] fp16, XOR-swizzled: sidx(q,m) = q*4096 + (((m>>3) ^ (q&7))<<3 | (m&7))
__global__ __launch_bounds__(1024, 4) void attn_kernel(const u16* __restrict__ Q, const u16* __restrict__ Kb,
                                                       const u16* __restrict__ Vt, u16* __restrict__ Ob) {
  __shared__ __align__(16) u16 S[16 * 4096];      // 128 KB (re-used for fp32 O-partials)
  __shared__ float zbuf[16][64];                  // per-row Z partials [row][wave*4+l4]
  __shared__ float invZs[16];
  const int tid  = threadIdx.x;
  const int lane = tid & 63, wave = tid >> 6;
  const int l15 = lane & 15, l4 = lane >> 4;
  const int h = blockIdx.y, b = blockIdx.z;
  const int bh = b * NHEADS + h;
  const int q0 = blockIdx.x * 16;
  const u16* Qh = Q  + ((size_t)bh * SEQ + q0) * HDIM;
  const u16* Kh = Kb + (size_t)bh * SEQ * HDIM;
  const u16* Vh = Vt + (size_t)bh * HDIM * SEQ;

  // Q fragments (rows q0..q0+15), Q already pre-scaled by 1/8. B-operand: l15 = q row.
  f16x8 qa0 = *(const f16x8*)(Qh + l15 * HDIM + l4 * 8);
  f16x8 qa1 = *(const f16x8*)(Qh + l15 * HDIM + 32 + l4 * 8);

  // ---- QK^T (swapped) + exp + Z partial; 2-deep prefetch ----
  const int m0base = wave * 256;
  float zp = 0.f;
  {
    const u16* kp0 = Kh + (size_t)(m0base + l15) * HDIM + l4 * 8;
    const u16* kp1 = Kh + (size_t)(m0base + 16 + l15) * HDIM + l4 * 8;
    f16x8 ka0 = *(const f16x8*)kp0;
    f16x8 ka1 = *(const f16x8*)(kp0 + 32);
    f16x8 kb0 = *(const f16x8*)kp1;
    f16x8 kb1 = *(const f16x8*)(kp1 + 32);
#pragma unroll 1
    for (int t = 0; t < 16; t += 2) {
      // ---- even tile t (operands in ka) ----
      {
        f32x4 acc = f32x4{0.f, 0.f, 0.f, 0.f};
        acc = mfma16(ka0, qa0, acc);
        acc = mfma16(ka1, qa1, acc);
        if (t + 2 < 16) {
          const u16* kpn = Kh + (size_t)(m0base + (t + 2) * 16 + l15) * HDIM + l4 * 8;
          ka0 = *(const f16x8*)kpn;
          ka1 = *(const f16x8*)(kpn + 32);
        }
        int m0 = m0base + t * 16;
        int g = (m0 >> 3) + (l4 >> 1);
        u16x4 pack;
#pragma unroll
        for (int j = 0; j < 4; j++) {
          float e = __expf(fminf(acc[j], 11.0f));
          zp += e;
          pack[j] = f2h_bits(e);
        }
        *(u16x4*)(S + (l15 << 12) + ((g ^ (l15 & 7)) << 3) + ((l4 & 1) << 2)) = pack;
      }
      // ---- odd tile t+1 (operands in kb) ----
      {
        f32x4 acc = f32x4{0.f, 0.f, 0.f, 0.f};
        acc = mfma16(kb0, qa0, acc);
        acc = mfma16(kb1, qa1, acc);
        if (t + 3 < 16) {
          const u16* kpn = Kh + (size_t)(m0base + (t + 3) * 16 + l15) * HDIM + l4 * 8;
          kb0 = *(const f16x8*)kpn;
          kb1 = *(const f16x8*)(kpn + 32);
        }
        int m0 = m0base + (t + 1) * 16;
        int g = (m0 >> 3) + (l4 >> 1);
        u16x4 pack;
#pragma unroll
        for (int j = 0; j < 4; j++) {
          float e = __expf(fminf(acc[j], 11.0f));
          zp += e;
          pack[j] = f2h_bits(e);
        }
        *(u16x4*)(S + (l15 << 12) + ((g ^ (l15 & 7)) << 3) + ((l4 & 1) << 2)) = pack;
      }
    }
  }
  zbuf[l15][(wave << 2) + l4] = zp;
  __syncthreads();

  // ---- exact top-k(409) per row; wave w owns row w ----
  {
    const u32 rbase = (u32)wave << 12;
    const u32 rx = (u32)(wave & 7) << 3;
    const u32 H = 0x80008000u;
    u32 X[8][4];
#pragma unroll
    for (int cc = 0; cc < 8; ++cc) {
      u32 c = (u32)cc * 64 + lane;
      u32x4 v = *(const u32x4*)(S + rbase + ((c << 3) ^ rx));
#pragma unroll
      for (int p = 0; p < 4; p++) X[cc][p] = v[p] | H;
    }
    // binary search on [0,0x7FFF]: t = smallest v with count(key > v) < KKEEP
    u32 lo = 0, hi = 0x7FFFu, c1 = 0;
    while (lo < hi) {
      u32 mid = (lo + hi) >> 1;
      u32 M1 = (mid + 1) * 0x10001u;
      u32 pc = 0;
#pragma unroll
      for (int cc = 0; cc < 8; ++cc)
#pragma unroll
        for (int p = 0; p < 4; p++) {
          u32 d = X[cc][p] - M1;
          pc += (d & H) >> 15;
        }
      u32 s = wred_add_u32(pc);                    // DPP reduce -> scalar
      u32 cnt = (s & 0xFFFFu) + (s >> 16);
      if (cnt < KKEEP) { hi = mid; c1 = cnt; } else lo = mid + 1;
    }
    const u32 t = lo;
    // Z reduce (partials from QK^T phase)
    float z = zbuf[wave][lane];
    z = wred_add_f32(z);
    if (lane == 0) invZs[wave] = 1.f / z;
    const int r = KKEEP - (int)c1;

    // write-back masked (unnormalized) weights
    const u32 M1t = (t + 1) * 0x10001u;
    const u32 M0t = t * 0x10001u;
    int run = 0;
#pragma unroll 1
    for (int cc = 0; cc < 8; ++cc) {
      u32 g1[4], eqm[4], eqany = 0;
#pragma unroll
      for (int p = 0; p < 4; p++) {
        u32 x = X[cc][p];
        g1[p] = (x - M1t) & H;
        u32 g0 = (x - M0t) & H;
        eqm[p] = g0 ^ g1[p];
        eqany |= eqm[p];
      }
      u32 c = (u32)cc * 64 + lane;
      u32* dst = (u32*)(S + rbase + ((c << 3) ^ rx));
      if (!__any(eqany != 0)) {                    // tie-free chunk: branchless masks
        u32x4 o;
#pragma unroll
        for (int p = 0; p < 4; p++) {
          u32 m = g1[p] | (g1[p] - (g1[p] >> 15));
          o[p] = X[cc][p] & m & 0x7FFF7FFFu;
        }
        *(u32x4*)dst = o;
      } else {                                     // rare: exact tie ranking
        u32 s = 0;
#pragma unroll
        for (int p = 0; p < 4; p++) s += eqm[p] >> 15;
        int ec = (int)((s & 0xFFFFu) + (s >> 16));
        int inc = ec;
#pragma unroll
        for (int o = 1; o < 64; o <<= 1) { int pfx = __shfl_up(inc, o); if (lane >= o) inc += pfx; }
        int rk = run + inc - ec;
        run += __shfl(inc, 63);
        u32x4 o;
#pragma unroll
        for (int p = 0; p < 4; p++) {
          u32 x = X[cc][p];
          u32 glo = (g1[p] >> 15) & 1u, ghi = g1[p] >> 31;
          u32 elo = (eqm[p] >> 15) & 1u, ehi = eqm[p] >> 31;
          u32 klo = glo | (elo & (rk < r ? 1u : 0u)); rk += (int)elo;
          u32 khi = ghi | (ehi & (rk < r ? 1u : 0u)); rk += (int)ehi;
          o[p] = x & ((klo ? 0xFFFFu : 0u) | (khi ? 0xFFFF0000u : 0u)) & 0x7FFF7FFFu;
        }
        *(u32x4*)dst = o;
      }
    }
  }
  __syncthreads();

  // ---- masked dense PV on unnormalized P̃; wave w covers its 256 keys ----
  f32x4 oacc[4];
#pragma unroll
  for (int dt = 0; dt < 4; dt++) oacc[dt] = f32x4{0.f, 0.f, 0.f, 0.f};
#pragma unroll 1
  for (int ks = 0; ks < 8; ++ks) {
    int mb = wave * 256 + ks * 32;
    u32 c = (u32)(mb >> 3) + l4;
    f16x8 pa = *(const f16x8*)(S + (l15 << 12) + (((c ^ (l15 & 7))) << 3));
#pragma unroll
    for (int dt = 0; dt < 4; ++dt) {
      const u16* vp = Vh + (size_t)(dt * 16 + l15) * SEQ + mb + l4 * 8;
      f16x8 vb = *(const f16x8*)vp;
      oacc[dt] = mfma16(pa, vb, oacc[dt]);
    }
  }
  __syncthreads();                 // P fully consumed -> S reusable for fp32 partials
  float* Op = (float*)S;           // [16 waves][16 rows][stride 65] fp32 = 66.5 KB
#pragma unroll
  for (int dt = 0; dt < 4; dt++)
#pragma unroll
    for (int j = 0; j < 4; j++)
      Op[(wave * 16 + l4 * 4 + j) * 65 + dt * 16 + l15] = oacc[dt][j];
  __syncthreads();
  {
    int row = tid >> 6, d = tid & 63;   // exactly 1024 outputs
    float v = 0.f;
#pragma unroll
    for (int w = 0; w < 16; ++w) v += Op[(w * 16 + row) * 65 + d];
    v *= invZs[row];                    // deferred softmax normalization
    Ob[((size_t)b * SEQ + q0 + row) * DIMC + h * HDIM + d] = f2h_bits(v);
  }
}

// ---------------- launch ----------------
extern "C" void kernel_launch(void* const* d_in, const int* in_sizes, int n_in,
                              void* d_out, int out_size, void* d_ws, size_t ws_size,
                              hipStream_t stream) {
  const float* x  = (const float*)d_in[0];
  const float* Wq = (const float*)d_in[1];
  const float* Wk = (const float*)d_in[2];
  const float* Wv = (const float*)d_in[3];
  const float* Wp = (const float*)d_in[4];
  const float* bp = (const float*)d_in[5];
  float* out = (float*)d_out;

  const size_t M = 2 * (size_t)SEQ;            // 8192
  const size_t XB = M * DIMC * 2;
  const size_t WB = (size_t)DIMC * DIMC * 2;

  char* w = (char*)d_ws;
  u16* xb   = (u16*)w; w += XB;
  u16* Wqb  = (u16*)w; w += WB;
  u16* Wkb  = (u16*)w; w += WB;
  u16* Wvb  = (u16*)w; w += WB;
  u16* Wpb  = (u16*)w; w += WB;
  u16* Qb   = (u16*)w; w += XB;
  u16* Kbuf = (u16*)w; w += XB;
  u16* Vtb  = (u16*)w; w += XB;
  u16* Obuf = (u16*)w; w += XB;

  cast_f32_to_f16<<<6144, 256, 0, stream>>>(x,  xb,  (int)(M * DIMC / 4));
  cast_f32_to_f16<<<576,  256, 0, stream>>>(Wq, Wqb, (int)(WB / 8));
  cast_f32_to_f16<<<576,  256, 0, stream>>>(Wk, Wkb, (int)(WB / 8));
  cast_f32_to_f16<<<576,  256, 0, stream>>>(Wv, Wvb, (int)(WB / 8));
  cast_f32_to_f16<<<576,  256, 0, stream>>>(Wp, Wpb, (int)(WB / 8));

  dim3 gg(64, 6);
  gemm_nt<0><<<gg, 256, 0, stream>>>(xb, Wqb, 0.125f, nullptr, Qb);    // Q pre-scaled
  gemm_nt<0><<<gg, 256, 0, stream>>>(xb, Wkb, 1.0f,   nullptr, Kbuf);
  gemm_nt<1><<<gg, 256, 0, stream>>>(xb, Wvb, 1.0f,   nullptr, Vtb);   // V transposed

  attn_kernel<<<dim3(256, NHEADS, 2), 1024, 0, stream>>>(Qb, Kbuf, Vtb, Obuf);

  gemm_nt<2><<<gg, 256, 0, stream>>>(Obuf, Wpb, 1.0f, bp, out);
}

// Round 8
// 1221.003 us; speedup vs baseline: 1.2974x; 1.0009x over previous
//
#include <hip/hip_runtime.h>

// SparseFinerAttention on MI355X — round 7 (r5 structure + DPP reduces + 2-deep K prefetch)
// B=2 N=4096 C=768 H=12 D=64 SCALE=1/8 K_keep=409

typedef unsigned short u16;
typedef unsigned int   u32;
typedef float    f32x4 __attribute__((ext_vector_type(4)));
typedef _Float16 f16x8 __attribute__((ext_vector_type(8)));
typedef u16      u16x8 __attribute__((ext_vector_type(8)));
typedef u16      u16x4 __attribute__((ext_vector_type(4)));
typedef u32      u32x4 __attribute__((ext_vector_type(4)));

#define NHEADS 12
#define SEQ    4096
#define DIMC   768
#define HDIM   64
#define KKEEP  409

__device__ __forceinline__ f32x4 mfma16(f16x8 a, f16x8 b, f32x4 c) {
  return __builtin_amdgcn_mfma_f32_16x16x32_f16(a, b, c, 0, 0, 0);
}
__device__ __forceinline__ u16 f2h_bits(float f) {
  return __builtin_bit_cast(u16, (_Float16)f);
}

// GPUOpen canonical wave64 DPP reduce (verified bit-correct in round 6):
// row_shr 1/2/4/8 + row_bcast 15/31, total lands in lane 63.
__device__ __forceinline__ u32 wred_add_u32(u32 x) {
  x += (u32)__builtin_amdgcn_update_dpp(0, (int)x, 0x111, 0xF, 0xF, true); // row_shr:1
  x += (u32)__builtin_amdgcn_update_dpp(0, (int)x, 0x112, 0xF, 0xF, true); // row_shr:2
  x += (u32)__builtin_amdgcn_update_dpp(0, (int)x, 0x114, 0xF, 0xF, true); // row_shr:4
  x += (u32)__builtin_amdgcn_update_dpp(0, (int)x, 0x118, 0xF, 0xF, true); // row_shr:8
  x += (u32)__builtin_amdgcn_update_dpp(0, (int)x, 0x142, 0xF, 0xF, true); // row_bcast:15
  x += (u32)__builtin_amdgcn_update_dpp(0, (int)x, 0x143, 0xF, 0xF, true); // row_bcast:31
  return (u32)__builtin_amdgcn_readlane((int)x, 63);
}
__device__ __forceinline__ float wred_add_f32(float x) {
#define _DPPF(ctrl) x += __builtin_bit_cast(float, __builtin_amdgcn_update_dpp( \
      0, __builtin_bit_cast(int, x), ctrl, 0xF, 0xF, true));
  _DPPF(0x111) _DPPF(0x112) _DPPF(0x114) _DPPF(0x118) _DPPF(0x142) _DPPF(0x143)
#undef _DPPF
  return __builtin_bit_cast(float, __builtin_amdgcn_readlane(__builtin_bit_cast(int, x), 63));
}

// ---------------- cast fp32 -> fp16 (vectorized) ----------------
__global__ __launch_bounds__(256) void cast_f32_to_f16(const float* __restrict__ in,
                                                       u16* __restrict__ out, int n4) {
  int i = blockIdx.x * 256 + threadIdx.x;
  if (i >= n4) return;
  float4 v = ((const float4*)in)[i];
  u16x4 o;
  o[0] = f2h_bits(v.x); o[1] = f2h_bits(v.y); o[2] = f2h_bits(v.z); o[3] = f2h_bits(v.w);
  ((u16x4*)out)[i] = o;
}

// ---------------- NT GEMM: C[M][768] = A[M][768] @ B[768][768]^T ----------------
template<int MODE>
__global__ __launch_bounds__(256) void gemm_nt(const u16* __restrict__ A, const u16* __restrict__ B,
                                               float scale, const float* __restrict__ bias,
                                               void* __restrict__ dstv) {
  __shared__ __align__(16) u16 As[128 * 64];
  __shared__ __align__(16) u16 Bs[128 * 64];
  const int tid  = threadIdx.x;
  const int lane = tid & 63, wave = tid >> 6;
  const int l15 = lane & 15, l4 = lane >> 4;
  const int row0 = blockIdx.x * 128, col0 = blockIdx.y * 128;
  const int wr = (wave >> 1) * 64, wc = (wave & 1) * 64;
  f32x4 acc[4][4];
#pragma unroll
  for (int i = 0; i < 4; i++)
#pragma unroll
    for (int j = 0; j < 4; j++) acc[i][j] = f32x4{0.f, 0.f, 0.f, 0.f};

  for (int k0 = 0; k0 < DIMC; k0 += 64) {
#pragma unroll
    for (int i = 0; i < 4; i++) {
      int id = tid + i * 256;
      int r = id >> 3, c = id & 7;
      f16x8 va = *(const f16x8*)(A + (size_t)(row0 + r) * DIMC + k0 + c * 8);
      f16x8 vb = *(const f16x8*)(B + (size_t)(col0 + r) * DIMC + k0 + c * 8);
      *(f16x8*)(As + r * 64 + ((c ^ (r & 7)) << 3)) = va;
      *(f16x8*)(Bs + r * 64 + ((c ^ (r & 7)) << 3)) = vb;
    }
    __syncthreads();
#pragma unroll
    for (int ks = 0; ks < 2; ++ks) {
      f16x8 af[4], bfr[4];
#pragma unroll
      for (int i = 0; i < 4; i++) {
        int r = wr + i * 16 + l15;
        int c = ks * 4 + l4;
        af[i] = *(const f16x8*)(As + r * 64 + ((c ^ (r & 7)) << 3));
        int r2 = wc + i * 16 + l15;
        bfr[i] = *(const f16x8*)(Bs + r2 * 64 + ((c ^ (r2 & 7)) << 3));
      }
#pragma unroll
      for (int i = 0; i < 4; i++)
#pragma unroll
        for (int j = 0; j < 4; j++) acc[i][j] = mfma16(af[i], bfr[j], acc[i][j]);
    }
    __syncthreads();
  }

#pragma unroll
  for (int i = 0; i < 4; i++) {
#pragma unroll
    for (int j = 0; j < 4; j++) {
      int rowb = row0 + wr + i * 16 + (l4 << 2);
      int col  = col0 + wc + j * 16 + l15;
      if (MODE == 2) {
        float* dst = (float*)dstv;
        float bv = bias[col];
#pragma unroll
        for (int jj = 0; jj < 4; jj++)
          dst[(size_t)(rowb + jj) * DIMC + col] = acc[i][j][jj] + bv;
      } else if (MODE == 0) {
        u16* dst = (u16*)dstv;
        int hh = col >> 6, d = col & 63;
#pragma unroll
        for (int jj = 0; jj < 4; jj++) {
          int row = rowb + jj;
          int bb = row >> 12, n = row & 4095;
          dst[(((size_t)bb * NHEADS + hh) * SEQ + n) * HDIM + d] = f2h_bits(acc[i][j][jj] * scale);
        }
      } else { // MODE 1: V transposed [b][h][d][n]
        u16* dst = (u16*)dstv;
        int hh = col >> 6, d = col & 63;
        int bb = rowb >> 12, nb = rowb & 4095;
        u16x4 pack;
#pragma unroll
        for (int jj = 0; jj < 4; jj++) pack[jj] = f2h_bits(acc[i][j][jj] * scale);
        *(u16x4*)(dst + (((size_t)bb * NHEADS + hh) * HDIM + d) * SEQ + nb) = pack;
      }
    }
  }
}

// ---------------- fused attention ----------------
// 1 workgroup (1024 thr, 16 waves) per (b, h, 16-row q block).  [round-5 structure]
// QK^T:  wave w keys [w*256,(w+1)*256) via swapped mfma(K,Q); 2-deep K prefetch;
//        stores fp16(exp(logit)) (monotone -> same top-k); f32 Z partials.
// top-k: wave w owns row w; SWAR packed binary search, DPP wave reduces (no bpermute).
// PV:    wave w covers its 256 keys on unnormalized P̃; invZ applied in epilogue.
// S: [16][4096] fp16, XOR-swizzled: sidx(q,m) = q*4096 + (((m>>3) ^ (q&7))<<3 | (m&7))
__global__ __launch_bounds__(1024, 4) void attn_kernel(const u16* __restrict__ Q, const u16* __restrict__ Kb,
                                                       const u16* __restrict__ Vt, u16* __restrict__ Ob) {
  __shared__ __align__(16) u16 S[16 * 4096];      // 128 KB (re-used for fp32 O-partials)
  __shared__ float zbuf[16][64];                  // per-row Z partials [row][wave*4+l4]
  __shared__ float invZs[16];
  const int tid  = threadIdx.x;
  const int lane = tid & 63, wave = tid >> 6;
  const int l15 = lane & 15, l4 = lane >> 4;
  const int h = blockIdx.y, b = blockIdx.z;
  const int bh = b * NHEADS + h;
  const int q0 = blockIdx.x * 16;
  const u16* Qh = Q  + ((size_t)bh * SEQ + q0) * HDIM;
  const u16* Kh = Kb + (size_t)bh * SEQ * HDIM;
  const u16* Vh = Vt + (size_t)bh * HDIM * SEQ;

  // Q fragments (rows q0..q0+15), Q already pre-scaled by 1/8. B-operand: l15 = q row.
  f16x8 qa0 = *(const f16x8*)(Qh + l15 * HDIM + l4 * 8);
  f16x8 qa1 = *(const f16x8*)(Qh + l15 * HDIM + 32 + l4 * 8);

  // ---- QK^T (swapped) + exp + Z partial; 2-deep prefetch ----
  const int m0base = wave * 256;
  float zp = 0.f;
  {
    const u16* kp0 = Kh + (size_t)(m0base + l15) * HDIM + l4 * 8;
    const u16* kp1 = Kh + (size_t)(m0base + 16 + l15) * HDIM + l4 * 8;
    f16x8 ka0 = *(const f16x8*)kp0;
    f16x8 ka1 = *(const f16x8*)(kp0 + 32);
    f16x8 kb0 = *(const f16x8*)kp1;
    f16x8 kb1 = *(const f16x8*)(kp1 + 32);
#pragma unroll 1
    for (int t = 0; t < 16; t += 2) {
      // ---- even tile t (operands in ka) ----
      {
        f32x4 acc = f32x4{0.f, 0.f, 0.f, 0.f};
        acc = mfma16(ka0, qa0, acc);
        acc = mfma16(ka1, qa1, acc);
        if (t + 2 < 16) {
          const u16* kpn = Kh + (size_t)(m0base + (t + 2) * 16 + l15) * HDIM + l4 * 8;
          ka0 = *(const f16x8*)kpn;
          ka1 = *(const f16x8*)(kpn + 32);
        }
        int m0 = m0base + t * 16;
        int g = (m0 >> 3) + (l4 >> 1);
        u16x4 pack;
#pragma unroll
        for (int j = 0; j < 4; j++) {
          float e = __expf(fminf(acc[j], 11.0f));
          zp += e;
          pack[j] = f2h_bits(e);
        }
        *(u16x4*)(S + (l15 << 12) + ((g ^ (l15 & 7)) << 3) + ((l4 & 1) << 2)) = pack;
      }
      // ---- odd tile t+1 (operands in kb) ----
      {
        f32x4 acc = f32x4{0.f, 0.f, 0.f, 0.f};
        acc = mfma16(kb0, qa0, acc);
        acc = mfma16(kb1, qa1, acc);
        if (t + 3 < 16) {
          const u16* kpn = Kh + (size_t)(m0base + (t + 3) * 16 + l15) * HDIM + l4 * 8;
          kb0 = *(const f16x8*)kpn;
          kb1 = *(const f16x8*)(kpn + 32);
        }
        int m0 = m0base + (t + 1) * 16;
        int g = (m0 >> 3) + (l4 >> 1);
        u16x4 pack;
#pragma unroll
        for (int j = 0; j < 4; j++) {
          float e = __expf(fminf(acc[j], 11.0f));
          zp += e;
          pack[j] = f2h_bits(e);
        }
        *(u16x4*)(S + (l15 << 12) + ((g ^ (l15 & 7)) << 3) + ((l4 & 1) << 2)) = pack;
      }
    }
  }
  zbuf[l15][(wave << 2) + l4] = zp;
  __syncthreads();

  // ---- exact top-k(409) per row; wave w owns row w ----
  {
    const u32 rbase = (u32)wave << 12;
    const u32 rx = (u32)(wave & 7) << 3;
    const u32 H = 0x80008000u;
    u32 X[8][4];
#pragma unroll
    for (int cc = 0; cc < 8; ++cc) {
      u32 c = (u32)cc * 64 + lane;
      u32x4 v = *(const u32x4*)(S + rbase + ((c << 3) ^ rx));
#pragma unroll
      for (int p = 0; p < 4; p++) X[cc][p] = v[p] | H;
    }
    // binary search on [0,0x7FFF]: t = smallest v with count(key > v) < KKEEP
    u32 lo = 0, hi = 0x7FFFu, c1 = 0;
    while (lo < hi) {
      u32 mid = (lo + hi) >> 1;
      u32 M1 = (mid + 1) * 0x10001u;
      u32 pc = 0;
#pragma unroll
      for (int cc = 0; cc < 8; ++cc)
#pragma unroll
        for (int p = 0; p < 4; p++) {
          u32 d = X[cc][p] - M1;
          pc += (d & H) >> 15;
        }
      u32 s = wred_add_u32(pc);                    // DPP reduce -> scalar
      u32 cnt = (s & 0xFFFFu) + (s >> 16);
      if (cnt < KKEEP) { hi = mid; c1 = cnt; } else lo = mid + 1;
    }
    const u32 t = lo;
    // Z reduce (partials from QK^T phase)
    float z = zbuf[wave][lane];
    z = wred_add_f32(z);
    if (lane == 0) invZs[wave] = 1.f / z;
    const int r = KKEEP - (int)c1;

    // write-back masked (unnormalized) weights
    const u32 M1t = (t + 1) * 0x10001u;
    const u32 M0t = t * 0x10001u;
    int run = 0;
#pragma unroll 1
    for (int cc = 0; cc < 8; ++cc) {
      u32 g1[4], eqm[4], eqany = 0;
#pragma unroll
      for (int p = 0; p < 4; p++) {
        u32 x = X[cc][p];
        g1[p] = (x - M1t) & H;
        u32 g0 = (x - M0t) & H;
        eqm[p] = g0 ^ g1[p];
        eqany |= eqm[p];
      }
      u32 c = (u32)cc * 64 + lane;
      u32* dst = (u32*)(S + rbase + ((c << 3) ^ rx));
      if (!__any(eqany != 0)) {                    // tie-free chunk: branchless masks
        u32x4 o;
#pragma unroll
        for (int p = 0; p < 4; p++) {
          u32 m = g1[p] | (g1[p] - (g1[p] >> 15));
          o[p] = X[cc][p] & m & 0x7FFF7FFFu;
        }
        *(u32x4*)dst = o;
      } else {                                     // rare: exact tie ranking
        u32 s = 0;
#pragma unroll
        for (int p = 0; p < 4; p++) s += eqm[p] >> 15;
        int ec = (int)((s & 0xFFFFu) + (s >> 16));
        int inc = ec;
#pragma unroll
        for (int o = 1; o < 64; o <<= 1) { int pfx = __shfl_up(inc, o); if (lane >= o) inc += pfx; }
        int rk = run + inc - ec;
        run += __shfl(inc, 63);
        u32x4 o;
#pragma unroll
        for (int p = 0; p < 4; p++) {
          u32 x = X[cc][p];
          u32 glo = (g1[p] >> 15) & 1u, ghi = g1[p] >> 31;
          u32 elo = (eqm[p] >> 15) & 1u, ehi = eqm[p] >> 31;
          u32 klo = glo | (elo & (rk < r ? 1u : 0u)); rk += (int)elo;
          u32 khi = ghi | (ehi & (rk < r ? 1u : 0u)); rk += (int)ehi;
          o[p] = x & ((klo ? 0xFFFFu : 0u) | (khi ? 0xFFFF0000u : 0u)) & 0x7FFF7FFFu;
        }
        *(u32x4*)dst = o;
      }
    }
  }
  __syncthreads();

  // ---- masked dense PV on unnormalized P̃; wave w covers its 256 keys ----
  f32x4 oacc[4];
#pragma unroll
  for (int dt = 0; dt < 4; dt++) oacc[dt] = f32x4{0.f, 0.f, 0.f, 0.f};
#pragma unroll 1
  for (int ks = 0; ks < 8; ++ks) {
    int mb = wave * 256 + ks * 32;
    u32 c = (u32)(mb >> 3) + l4;
    f16x8 pa = *(const f16x8*)(S + (l15 << 12) + (((c ^ (l15 & 7))) << 3));
#pragma unroll
    for (int dt = 0; dt < 4; ++dt) {
      const u16* vp = Vh + (size_t)(dt * 16 + l15) * SEQ + mb + l4 * 8;
      f16x8 vb = *(const f16x8*)vp;
      oacc[dt] = mfma16(pa, vb, oacc[dt]);
    }
  }
  __syncthreads();                 // P fully consumed -> S reusable for fp32 partials
  float* Op = (float*)S;           // [16 waves][16 rows][stride 65] fp32 = 66.5 KB
#pragma unroll
  for (int dt = 0; dt < 4; dt++)
#pragma unroll
    for (int j = 0; j < 4; j++)
      Op[(wave * 16 + l4 * 4 + j) * 65 + dt * 16 + l15] = oacc[dt][j];
  __syncthreads();
  {
    int row = tid >> 6, d = tid & 63;   // exactly 1024 outputs
    float v = 0.f;
#pragma unroll
    for (int w = 0; w < 16; ++w) v += Op[(w * 16 + row) * 65 + d];
    v *= invZs[row];                    // deferred softmax normalization
    Ob[((size_t)b * SEQ + q0 + row) * DIMC + h * HDIM + d] = f2h_bits(v);
  }
}

// ---------------- launch ----------------
extern "C" void kernel_launch(void* const* d_in, const int* in_sizes, int n_in,
                              void* d_out, int out_size, void* d_ws, size_t ws_size,
                              hipStream_t stream) {
  const float* x  = (const float*)d_in[0];
  const float* Wq = (const float*)d_in[1];
  const float* Wk = (const float*)d_in[2];
  const float* Wv = (const float*)d_in[3];
  const float* Wp = (const float*)d_in[4];
  const float* bp = (const float*)d_in[5];
  float* out = (float*)d_out;

  const size_t M = 2 * (size_t)SEQ;            // 8192
  const size_t XB = M * DIMC * 2;
  const size_t WB = (size_t)DIMC * DIMC * 2;

  char* w = (char*)d_ws;
  u16* xb   = (u16*)w; w += XB;
  u16* Wqb  = (u16*)w; w += WB;
  u16* Wkb  = (u16*)w; w += WB;
  u16* Wvb  = (u16*)w; w += WB;
  u16* Wpb  = (u16*)w; w += WB;
  u16* Qb   = (u16*)w; w += XB;
  u16* Kbuf = (u16*)w; w += XB;
  u16* Vtb  = (u16*)w; w += XB;
  u16* Obuf = (u16*)w; w += XB;

  cast_f32_to_f16<<<6144, 256, 0, stream>>>(x,  xb,  (int)(M * DIMC / 4));
  cast_f32_to_f16<<<576,  256, 0, stream>>>(Wq, Wqb, (int)(WB / 8));
  cast_f32_to_f16<<<576,  256, 0, stream>>>(Wk, Wkb, (int)(WB / 8));
  cast_f32_to_f16<<<576,  256, 0, stream>>>(Wv, Wvb, (int)(WB / 8));
  cast_f32_to_f16<<<576,  256, 0, stream>>>(Wp, Wpb, (int)(WB / 8));

  dim3 gg(64, 6);
  gemm_nt<0><<<gg, 256, 0, stream>>>(xb, Wqb, 0.125f, nullptr, Qb);    // Q pre-scaled
  gemm_nt<0><<<gg, 256, 0, stream>>>(xb, Wkb, 1.0f,   nullptr, Kbuf);
  gemm_nt<1><<<gg, 256, 0, stream>>>(xb, Wvb, 1.0f,   nullptr, Vtb);   // V transposed

  attn_kernel<<<dim3(256, NHEADS, 2), 1024, 0, stream>>>(Qb, Kbuf, Vtb, Obuf);

  gemm_nt<2><<<gg, 256, 0, stream>>>(Obuf, Wpb, 1.0f, bp, out);
}